// Round 4
// baseline (117.166 us; speedup 1.0000x reference)
//
#include <hip/hip_runtime.h>
#include <hip/hip_bf16.h>

// Problem constants (setup_inputs is fixed):
//   x: (B=16, T=2048, D=64) fp32, pred_len=720, k=16, low_freq=1
//   out: (16, 2768, 64) fp32
#define B_SZ 16
#define T_SZ 2048
#define D_SZ 64
#define M_SZ 1024          // complex FFT length (T/2)
#define K_SEL 16
#define TOUT 2768          // T + pred_len
#define TPT 8              // taus per thread in synth
#define TAUS_PER_BLOCK (4 * TPT)                       // 32
#define NCHUNK ((TOUT + TAUS_PER_BLOCK - 1) / TAUS_PER_BLOCK)  // 87

// ---------------------------------------------------------------------------
// Kernel 0: transpose x (b,t,d) -> xT (b,d,t) so FFT loads are contiguous.
// 64x64 fp32 tile via padded LDS; fully coalesced both sides.
// ---------------------------------------------------------------------------
__global__ __launch_bounds__(256) void transpose_kernel(
    const float* __restrict__ x, float* __restrict__ xT)
{
    __shared__ float tile[64][65];
    const int b    = blockIdx.y;
    const int t0   = blockIdx.x * 64;
    const int lane = threadIdx.x & 63;
    const int row4 = threadIdx.x >> 6;      // 0..3

    #pragma unroll
    for (int rr = 0; rr < 16; ++rr) {
        int r = rr * 4 + row4;
        tile[r][lane] = x[((size_t)b * T_SZ + t0 + r) * D_SZ + lane];
    }
    __syncthreads();
    #pragma unroll
    for (int rr = 0; rr < 16; ++rr) {
        int d = rr * 4 + row4;
        xT[((size_t)b * D_SZ + d) * T_SZ + t0 + lane] = tile[lane][d];
    }
}

// ---------------------------------------------------------------------------
// Kernel 1: per-(b,d) real FFT of length 2048 (complex FFT of 1024 + unpack),
// then top-16 by |X|^2 with register-resident wave-local selection.
// ---------------------------------------------------------------------------
__global__ __launch_bounds__(256) void fft_topk_kernel(
    const float* __restrict__ xT,
    int* __restrict__ sel_j,     // (1024, 16)
    float* __restrict__ sel_re,  // (1024, 16)
    float* __restrict__ sel_im)  // (1024, 16)
{
    __shared__ float a_re[M_SZ], a_im[M_SZ];
    __shared__ float tw_re[M_SZ / 2], tw_im[M_SZ / 2];
    __shared__ float X_re[M_SZ], X_im[M_SZ];
    __shared__ float mag2[M_SZ];
    __shared__ float cand_v[64];
    __shared__ int   cand_j[64];

    const int bd   = blockIdx.x;         // b*64 + d
    const int tid  = threadIdx.x;
    const int lane = tid & 63;
    const int w    = tid >> 6;           // wave id 0..3

    // Twiddles: tw[k] = e^{-2*pi*i*k/1024} (sub-ulp via cospif/sinpif).
    for (int k = tid; k < M_SZ / 2; k += 256) {
        float a = (float)k * (1.0f / 512.0f);
        tw_re[k] =  cospif(a);
        tw_im[k] = -sinpif(a);
    }

    // Coalesced float2 loads of xT row; even/odd packed, bit-reversed store.
    const float2* xb2 = (const float2*)(xT + (size_t)bd * T_SZ);
    #pragma unroll
    for (int r = 0; r < 4; ++r) {
        int m = tid + 256 * r;
        float2 v = xb2[m];
        int pos = __brev((unsigned)m) >> 22;   // 10-bit reversal
        a_re[pos] = v.x;
        a_im[pos] = v.y;
    }
    __syncthreads();

    // 10 radix-2 DIT stages.
    for (int s = 0; s < 10; ++s) {
        #pragma unroll 2
        for (int q = tid; q < M_SZ / 2; q += 256) {
            int half = 1 << s;
            int pos  = q & (half - 1);
            int i0   = ((q >> s) << (s + 1)) + pos;
            int i1   = i0 + half;
            int twi  = pos << (9 - s);
            float wr = tw_re[twi], wi = tw_im[twi];
            float br = a_re[i1],  bi = a_im[i1];
            float tr = fmaf(wr, br, -wi * bi);
            float ti = fmaf(wr, bi,  wi * br);
            float ar = a_re[i0],  ai = a_im[i0];
            a_re[i0] = ar + tr;  a_im[i0] = ai + ti;
            a_re[i1] = ar - tr;  a_im[i1] = ai - ti;
        }
        __syncthreads();
    }

    // Real-FFT unpack: X[j] = E[j] + W_2048^j * O[j], j = 1..1023.
    for (int j = tid; j < M_SZ; j += 256) {
        if (j == 0) {
            X_re[0] = 0.0f; X_im[0] = 0.0f; mag2[0] = -2.0f;  // excluded bin
            continue;
        }
        int jc = M_SZ - j;
        float zr = a_re[j],  zi = a_im[j];
        float cr = a_re[jc], ci = a_im[jc];
        float er = 0.5f * (zr + cr), ei = 0.5f * (zi - ci);
        float ur = zr - cr,  vv = zi + ci;
        float orr = 0.5f * vv, oii = -0.5f * ur;
        float a  = (float)j * (1.0f / 1024.0f);
        float twr =  cospif(a);
        float twq = -sinpif(a);
        float xr = er + twr * orr - twq * oii;
        float xi = ei + twr * oii + twq * orr;
        X_re[j] = xr; X_im[j] = xi;
        mag2[j] = xr * xr + xi * xi;
    }
    __syncthreads();

    // Stage 1: each wave selects top-16 of its 256-bin quarter, in registers,
    // shfl-only (no barriers). Lower index wins ties (matches lax.top_k).
    float v[4]; int jj[4];
    #pragma unroll
    for (int r = 0; r < 4; ++r) {
        jj[r] = w * 256 + r * 64 + lane;
        v[r]  = mag2[jj[r]];
    }
    float my_v = -3.0f; int my_j = 0;
    for (int it = 0; it < K_SEL; ++it) {
        float bv = -2.5f; int bj = 1 << 20;
        #pragma unroll
        for (int r = 0; r < 4; ++r)          // jj ascending: strict > keeps low j
            if (v[r] > bv) { bv = v[r]; bj = jj[r]; }
        #pragma unroll
        for (int off = 32; off; off >>= 1) {
            float ov = __shfl_xor(bv, off);
            int   oj = __shfl_xor(bj, off);
            if (ov > bv || (ov == bv && oj < bj)) { bv = ov; bj = oj; }
        }
        if (lane == it) { my_v = bv; my_j = bj; }
        #pragma unroll
        for (int r = 0; r < 4; ++r)
            if (jj[r] == bj) v[r] = -2.0f;
    }
    if (lane < K_SEL) { cand_v[w * K_SEL + lane] = my_v; cand_j[w * K_SEL + lane] = my_j; }
    __syncthreads();

    // Stage 2: wave 0 merges 64 candidates (one per lane) -> global top-16.
    if (w == 0) {
        float cv = cand_v[lane]; int cj = cand_j[lane];
        int out_j = 0;
        for (int it = 0; it < K_SEL; ++it) {
            float rv = cv; int rj = cj;
            #pragma unroll
            for (int off = 32; off; off >>= 1) {
                float ov = __shfl_xor(rv, off);
                int   oj = __shfl_xor(rj, off);
                if (ov > rv || (ov == rv && oj < rj)) { rv = ov; rj = oj; }
            }
            if (lane == it) out_j = rj;
            if (cj == rj) cv = -2.0f;
        }
        if (lane < K_SEL) {
            int j = out_j;
            sel_j [bd * K_SEL + lane] = j;
            sel_re[bd * K_SEL + lane] = X_re[j];
            sel_im[bd * K_SEL + lane] = X_im[j];
        }
    }
}

// ---------------------------------------------------------------------------
// Kernel 2: out[b,tau,d] = (1/1024) * sum_q ( Re_q*cos(2pi j_q tau/2048)
//                                           - Im_q*sin(2pi j_q tau/2048) )
// Selection triples live in registers (64B coalesced load per lane);
// TPT taus per thread amortize the load. Exact (j*tau mod 2048)/2048
// revolutions feed v_cos/v_sin directly.
// ---------------------------------------------------------------------------
__global__ __launch_bounds__(256) void synth_kernel(
    const int*   __restrict__ sel_j,
    const float* __restrict__ sel_re,
    const float* __restrict__ sel_im,
    float* __restrict__ out)
{
    const int bid   = blockIdx.x;          // b * NCHUNK + chunk
    const int b     = bid / NCHUNK;
    const int chunk = bid - b * NCHUNK;
    const int tid   = threadIdx.x;
    const int d     = tid & 63;
    const int tg    = tid >> 6;            // 0..3

    const int g = (b * D_SZ + d) * K_SEL;  // 16-elem aligned => 64B aligned
    int   j [K_SEL];
    float re[K_SEL];
    float im[K_SEL];
    const int4*   pj = (const int4*)  (sel_j  + g);
    const float4* pr = (const float4*)(sel_re + g);
    const float4* pi = (const float4*)(sel_im + g);
    #pragma unroll
    for (int r = 0; r < 4; ++r) {
        int4   a = pj[r];
        float4 c = pr[r];
        float4 s = pi[r];
        j [4*r+0] = a.x; j [4*r+1] = a.y; j [4*r+2] = a.z; j [4*r+3] = a.w;
        re[4*r+0] = c.x; re[4*r+1] = c.y; re[4*r+2] = c.z; re[4*r+3] = c.w;
        im[4*r+0] = s.x; im[4*r+1] = s.y; im[4*r+2] = s.z; im[4*r+3] = s.w;
    }

    const int tau0 = chunk * TAUS_PER_BLOCK + tg * TPT;
    #pragma unroll
    for (int u = 0; u < TPT; ++u) {
        int tau = tau0 + u;
        if (tau >= TOUT) break;
        float acc = 0.0f;
        #pragma unroll
        for (int q = 0; q < K_SEL; ++q) {
            int   ph = (j[q] * tau) & (T_SZ - 1);        // exact mod 2048
            float r  = (float)ph * (1.0f / (float)T_SZ); // exact /2^11
            float c  = __builtin_amdgcn_cosf(r);         // cos(2*pi*r)
            float s  = __builtin_amdgcn_sinf(r);         // sin(2*pi*r)
            acc = fmaf(re[q], c, acc);
            acc = fmaf(-im[q], s, acc);
        }
        out[((size_t)b * TOUT + tau) * D_SZ + d] = acc * (1.0f / 1024.0f);
    }
}

// ---------------------------------------------------------------------------
extern "C" void kernel_launch(void* const* d_in, const int* in_sizes, int n_in,
                              void* d_out, int out_size, void* d_ws, size_t ws_size,
                              hipStream_t stream) {
    const float* x = (const float*)d_in[0];

    // ws layout: xT (8 MB) | sel_j (64KB) | sel_re (64KB) | sel_im (64KB)
    float* xT     = (float*)d_ws;
    char*  base   = (char*)d_ws + (size_t)B_SZ * T_SZ * D_SZ * 4;
    int*   sel_j  = (int*)base;
    float* sel_re = (float*)(base + (size_t)B_SZ * D_SZ * K_SEL * 4);
    float* sel_im = (float*)(base + (size_t)2 * B_SZ * D_SZ * K_SEL * 4);

    transpose_kernel<<<dim3(T_SZ / 64, B_SZ), dim3(256), 0, stream>>>(x, xT);

    fft_topk_kernel<<<dim3(B_SZ * D_SZ), dim3(256), 0, stream>>>(
        xT, sel_j, sel_re, sel_im);

    synth_kernel<<<dim3(B_SZ * NCHUNK), dim3(256), 0, stream>>>(
        sel_j, sel_re, sel_im, (float*)d_out);
}

// Round 6
// 110.048 us; speedup vs baseline: 1.0647x; 1.0647x over previous
//
#include <hip/hip_runtime.h>
#include <hip/hip_bf16.h>

// Problem constants (setup_inputs is fixed):
//   x: (B=16, T=2048, D=64) fp32, pred_len=720, k=16, low_freq=1
//   out: (16, 2768, 64) fp32
#define B_SZ 16
#define T_SZ 2048
#define D_SZ 64
#define M_SZ 1024          // complex FFT length (T/2)
#define K_SEL 16
#define TOUT 2768          // T + pred_len
#define TPT 16             // taus per thread in synth (recurrence length)
#define TAUS_PER_BLOCK (4 * TPT)                       // 64
#define NCHUNK ((TOUT + TAUS_PER_BLOCK - 1) / TAUS_PER_BLOCK)  // 44

// ---------------------------------------------------------------------------
// Kernel 1: per-(b,d) real FFT of length 2048 (complex FFT of 1024 + unpack),
// then top-16 by |X|^2 with register-resident wave-local selection.
// Input loads are strided (d fixed, t varies); round-3-vs-4 A/B showed this
// equals the transposed/coalesced path, so no transpose pass.
// ---------------------------------------------------------------------------
__global__ __launch_bounds__(256) void fft_topk_kernel(
    const float* __restrict__ x,
    int* __restrict__ sel_j,     // (1024, 16)
    float* __restrict__ sel_re,  // (1024, 16)
    float* __restrict__ sel_im)  // (1024, 16)
{
    __shared__ float a_re[M_SZ], a_im[M_SZ];
    __shared__ float tw_re[M_SZ / 2], tw_im[M_SZ / 2];
    __shared__ float X_re[M_SZ], X_im[M_SZ];
    __shared__ float mag2[M_SZ];
    __shared__ float cand_v[64];
    __shared__ int   cand_j[64];

    const int bd   = blockIdx.x;         // b*64 + d
    const int b    = bd >> 6;
    const int d    = bd & 63;
    const int tid  = threadIdx.x;
    const int lane = tid & 63;
    const int w    = tid >> 6;           // wave id 0..3

    // Twiddles: tw[k] = e^{-2*pi*i*k/1024} (sub-ulp via cospif/sinpif).
    for (int k = tid; k < M_SZ / 2; k += 256) {
        float a = (float)k * (1.0f / 512.0f);
        tw_re[k] =  cospif(a);
        tw_im[k] = -sinpif(a);
    }

    // Load x[b, :, d]; even/odd packed, bit-reversed positions (DIT).
    const float* xb = x + (size_t)b * T_SZ * D_SZ + d;
    #pragma unroll
    for (int r = 0; r < 4; ++r) {
        int m = tid + 256 * r;
        float xe = xb[(2 * m) * D_SZ];
        float xo = xb[(2 * m + 1) * D_SZ];
        int pos = __brev((unsigned)m) >> 22;   // 10-bit reversal
        a_re[pos] = xe;
        a_im[pos] = xo;
    }
    __syncthreads();

    // 10 radix-2 DIT stages; butterflies disjoint within a stage.
    for (int s = 0; s < 10; ++s) {
        #pragma unroll 2
        for (int q = tid; q < M_SZ / 2; q += 256) {
            int half = 1 << s;
            int pos  = q & (half - 1);
            int i0   = ((q >> s) << (s + 1)) + pos;
            int i1   = i0 + half;
            int twi  = pos << (9 - s);
            float wr = tw_re[twi], wi = tw_im[twi];
            float br = a_re[i1],  bi = a_im[i1];
            float tr = fmaf(wr, br, -wi * bi);
            float ti = fmaf(wr, bi,  wi * br);
            float ar = a_re[i0],  ai = a_im[i0];
            a_re[i0] = ar + tr;  a_im[i0] = ai + ti;
            a_re[i1] = ar - tr;  a_im[i1] = ai - ti;
        }
        __syncthreads();
    }

    // Real-FFT unpack: X[j] = E[j] + W_2048^j * O[j], j = 1..1023.
    for (int j = tid; j < M_SZ; j += 256) {
        if (j == 0) {
            X_re[0] = 0.0f; X_im[0] = 0.0f; mag2[0] = -2.0f;  // excluded bin
            continue;
        }
        int jc = M_SZ - j;
        float zr = a_re[j],  zi = a_im[j];
        float cr = a_re[jc], ci = a_im[jc];
        float er = 0.5f * (zr + cr), ei = 0.5f * (zi - ci);
        float ur = zr - cr,  vv = zi + ci;
        float orr = 0.5f * vv, oii = -0.5f * ur;
        float a  = (float)j * (1.0f / 1024.0f);
        float twr =  cospif(a);
        float twq = -sinpif(a);
        float xr = er + twr * orr - twq * oii;
        float xi = ei + twr * oii + twq * orr;
        X_re[j] = xr; X_im[j] = xi;
        mag2[j] = xr * xr + xi * xi;
    }
    __syncthreads();

    // Stage 1: each wave selects top-16 of its 256-bin quarter, in registers,
    // shfl-only (no barriers). Lower index wins ties (matches lax.top_k).
    float v[4]; int jj[4];
    #pragma unroll
    for (int r = 0; r < 4; ++r) {
        jj[r] = w * 256 + r * 64 + lane;
        v[r]  = mag2[jj[r]];
    }
    float my_v = -3.0f; int my_j = 0;
    for (int it = 0; it < K_SEL; ++it) {
        float bv = -2.5f; int bj = 1 << 20;
        #pragma unroll
        for (int r = 0; r < 4; ++r)          // jj ascending: strict > keeps low j
            if (v[r] > bv) { bv = v[r]; bj = jj[r]; }
        #pragma unroll
        for (int off = 32; off; off >>= 1) {
            float ov = __shfl_xor(bv, off);
            int   oj = __shfl_xor(bj, off);
            if (ov > bv || (ov == bv && oj < bj)) { bv = ov; bj = oj; }
        }
        if (lane == it) { my_v = bv; my_j = bj; }
        #pragma unroll
        for (int r = 0; r < 4; ++r)
            if (jj[r] == bj) v[r] = -2.0f;
    }
    if (lane < K_SEL) { cand_v[w * K_SEL + lane] = my_v; cand_j[w * K_SEL + lane] = my_j; }
    __syncthreads();

    // Stage 2: wave 0 merges 64 candidates (one per lane) -> global top-16.
    if (w == 0) {
        float cv = cand_v[lane]; int cj = cand_j[lane];
        int out_j = 0;
        for (int it = 0; it < K_SEL; ++it) {
            float rv = cv; int rj = cj;
            #pragma unroll
            for (int off = 32; off; off >>= 1) {
                float ov = __shfl_xor(rv, off);
                int   oj = __shfl_xor(rj, off);
                if (ov > rv || (ov == rv && oj < rj)) { rv = ov; rj = oj; }
            }
            if (lane == it) out_j = rj;
            if (cj == rj) cv = -2.0f;
        }
        if (lane < K_SEL) {
            int j = out_j;
            sel_j [bd * K_SEL + lane] = j;
            sel_re[bd * K_SEL + lane] = X_re[j];
            sel_im[bd * K_SEL + lane] = X_im[j];
        }
    }
}

// ---------------------------------------------------------------------------
// Kernel 2: out[b,tau,d] = (1/1024) * sum_q ( Re_q*cos(2pi j_q tau/2048)
//                                           - Im_q*sin(2pi j_q tau/2048) )
// Phase recurrence: per q, evaluate cos/sin exactly at tau0 (revolution-
// domain, exact argument), then rotate by cis(2pi j/2048) for TPT steps.
// Selection triples live in registers (64B coalesced loads per lane).
// Block = 4 tau-groups x 64 d => coalesced 256B output rows.
// ---------------------------------------------------------------------------
__global__ __launch_bounds__(256) void synth_kernel(
    const int*   __restrict__ sel_j,
    const float* __restrict__ sel_re,
    const float* __restrict__ sel_im,
    float* __restrict__ out)
{
    const int bid   = blockIdx.x;          // b * NCHUNK + chunk
    const int b     = bid / NCHUNK;
    const int chunk = bid - b * NCHUNK;
    const int tid   = threadIdx.x;
    const int d     = tid & 63;
    const int tg    = tid >> 6;            // 0..3

    const int tau0 = chunk * TAUS_PER_BLOCK + tg * TPT;
    if (tau0 >= TOUT) return;              // whole thread out of range
    const int nu = (TOUT - tau0 < TPT) ? (TOUT - tau0) : TPT;

    const int g = (b * D_SZ + d) * K_SEL;  // 16-elem aligned => 64B aligned
    int   j [K_SEL];
    float re[K_SEL];
    float im[K_SEL];
    const int4*   pj = (const int4*)  (sel_j  + g);
    const float4* pr = (const float4*)(sel_re + g);
    const float4* pi = (const float4*)(sel_im + g);
    #pragma unroll
    for (int r = 0; r < 4; ++r) {
        int4   a = pj[r];
        float4 c = pr[r];
        float4 s = pi[r];
        j [4*r+0] = a.x; j [4*r+1] = a.y; j [4*r+2] = a.z; j [4*r+3] = a.w;
        re[4*r+0] = c.x; re[4*r+1] = c.y; re[4*r+2] = c.z; re[4*r+3] = c.w;
        im[4*r+0] = s.x; im[4*r+1] = s.y; im[4*r+2] = s.z; im[4*r+3] = s.w;
    }

    float acc[TPT];
    #pragma unroll
    for (int u = 0; u < TPT; ++u) acc[u] = 0.0f;

    #pragma unroll
    for (int q = 0; q < K_SEL; ++q) {
        // Exact initial phase (revolutions) and exact step rotation.
        int   ph0 = (j[q] * tau0) & (T_SZ - 1);
        float r0  = (float)ph0  * (1.0f / (float)T_SZ);   // exact /2^11
        float rw  = (float)j[q] * (1.0f / (float)T_SZ);   // exact /2^11
        float c   = __builtin_amdgcn_cosf(r0);            // cos(2*pi*r0)
        float s   = __builtin_amdgcn_sinf(r0);
        float cw  = __builtin_amdgcn_cosf(rw);
        float sw  = __builtin_amdgcn_sinf(rw);
        #pragma unroll
        for (int u = 0; u < TPT; ++u) {
            acc[u] = fmaf(re[q], c, acc[u]);
            acc[u] = fmaf(-im[q], s, acc[u]);
            float cn = fmaf(c, cw, -s * sw);
            float sn = fmaf(s, cw,  c * sw);
            c = cn; s = sn;
        }
    }

    float* ob = out + ((size_t)b * TOUT + tau0) * D_SZ + d;
    #pragma unroll
    for (int u = 0; u < TPT; ++u) {
        if (u < nu) ob[(size_t)u * D_SZ] = acc[u] * (1.0f / 1024.0f);
    }
}

// ---------------------------------------------------------------------------
extern "C" void kernel_launch(void* const* d_in, const int* in_sizes, int n_in,
                              void* d_out, int out_size, void* d_ws, size_t ws_size,
                              hipStream_t stream) {
    const float* x = (const float*)d_in[0];

    // ws layout: sel_j (64KB) | sel_re (64KB) | sel_im (64KB)
    int*   sel_j  = (int*)d_ws;
    float* sel_re = (float*)((char*)d_ws + (size_t)B_SZ * D_SZ * K_SEL * 4);
    float* sel_im = (float*)((char*)d_ws + (size_t)2 * B_SZ * D_SZ * K_SEL * 4);

    fft_topk_kernel<<<dim3(B_SZ * D_SZ), dim3(256), 0, stream>>>(
        x, sel_j, sel_re, sel_im);

    synth_kernel<<<dim3(B_SZ * NCHUNK), dim3(256), 0, stream>>>(
        sel_j, sel_re, sel_im, (float*)d_out);
}

// Round 7
// 107.225 us; speedup vs baseline: 1.0927x; 1.0263x over previous
//
#include <hip/hip_runtime.h>
#include <hip/hip_bf16.h>

// Problem constants (setup_inputs is fixed):
//   x: (B=16, T=2048, D=64) fp32, pred_len=720, k=16, low_freq=1
//   out: (16, 2768, 64) fp32
#define B_SZ 16
#define T_SZ 2048
#define D_SZ 64
#define M_SZ 1024          // complex FFT length (T/2)
#define K_SEL 16
#define TOUT 2768          // T + pred_len
#define TPT 16             // taus per thread in synth (recurrence length)
#define TAUS_PER_BLOCK (4 * TPT)                       // 64
#define NCHUNK ((TOUT + TAUS_PER_BLOCK - 1) / TAUS_PER_BLOCK)  // 44

// base-4 digit reversal of a 10-bit index (5 digits); involution.
__device__ __forceinline__ int digitrev4(int m) {
    int v = __brev((unsigned)m) >> 22;                 // 10-bit bit reversal
    return ((v & 0x155) << 1) | ((v >> 1) & 0x155);    // swap bit pairs
}

// ---------------------------------------------------------------------------
// Kernel 1: per-(b,d) real FFT of length 2048 via radix-4 complex FFT of
// 1024 (5 stages, in-place, digit-reversed loads) + in-place real unpack,
// then top-16 by |X|^2 with register-resident wave-local selection.
// ---------------------------------------------------------------------------
__global__ __launch_bounds__(256) void fft_topk_kernel(
    const float* __restrict__ x,
    int* __restrict__ sel_j,     // (1024, 16)
    float* __restrict__ sel_re,  // (1024, 16)
    float* __restrict__ sel_im)  // (1024, 16)
{
    __shared__ __align__(16) float a_re[M_SZ], a_im[M_SZ];
    __shared__ float tw_re[768], tw_im[768];   // W_1024^k, k=0..767
    __shared__ float mag2[M_SZ];
    __shared__ float cand_v[64];
    __shared__ int   cand_j[64];

    const int bd   = blockIdx.x;         // b*64 + d
    const int b    = bd >> 6;
    const int d    = bd & 63;
    const int tid  = threadIdx.x;
    const int lane = tid & 63;
    const int w    = tid >> 6;           // wave id 0..3

    // Issue global loads FIRST (HBM latency hides under twiddle fill).
    // Target slot 'pos' is consecutive per thread (conflict-free LDS write);
    // source index m = digitrev4(pos) (involution) -> DIT natural order.
    const float* xb = x + (size_t)b * T_SZ * D_SZ + d;
    float xe[4], xo[4];
    #pragma unroll
    for (int r = 0; r < 4; ++r) {
        int pos = tid + 256 * r;
        int m   = digitrev4(pos);
        xe[r] = xb[(2 * m) * D_SZ];
        xo[r] = xb[(2 * m + 1) * D_SZ];
    }

    // Twiddles: tw[k] = e^{-2*pi*i*k/1024} (sub-ulp via cospif/sinpif).
    for (int k = tid; k < 768; k += 256) {
        float a = (float)k * (1.0f / 512.0f);
        tw_re[k] =  cospif(a);
        tw_im[k] = -sinpif(a);
    }

    #pragma unroll
    for (int r = 0; r < 4; ++r) {
        int pos = tid + 256 * r;
        a_re[pos] = xe[r];
        a_im[pos] = xo[r];
    }
    __syncthreads();

    // ---- Stage 0 (q=1): twiddle-free, contiguous float4, in-place. ----
    {
        float4* pr4 = reinterpret_cast<float4*>(a_re);
        float4* pi4 = reinterpret_cast<float4*>(a_im);
        float4 vr = pr4[tid];
        float4 vi = pi4[tid];
        float t0r = vr.x + vr.z, t0i = vi.x + vi.z;
        float t1r = vr.x - vr.z, t1i = vi.x - vi.z;
        float t2r = vr.y + vr.w, t2i = vi.y + vi.w;
        float t3r = vr.y - vr.w, t3i = vi.y - vi.w;
        // X0 = t0+t2; X1 = t1 - i*t3; X2 = t0-t2; X3 = t1 + i*t3
        vr.x = t0r + t2r;  vi.x = t0i + t2i;
        vr.y = t1r + t3i;  vi.y = t1i - t3r;
        vr.z = t0r - t2r;  vi.z = t0i - t2i;
        vr.w = t1r - t3i;  vi.w = t1i + t3r;
        pr4[tid] = vr;
        pi4[tid] = vi;
    }
    __syncthreads();

    // ---- Stages 1..4 (q=4,16,64,256): 256 radix-4 butterflies each. ----
    #pragma unroll
    for (int s = 1; s < 5; ++s) {
        const int q   = 1 << (2 * s);
        const int pos = tid & (q - 1);
        const int i0  = ((tid >> (2 * s)) << (2 * s + 2)) + pos;
        const int e   = pos << (8 - 2 * s);

        float w1r = tw_re[e],     w1i = tw_im[e];
        float w2r = tw_re[2 * e], w2i = tw_im[2 * e];
        float w3r = tw_re[3 * e], w3i = tw_im[3 * e];

        float b0r = a_re[i0],         b0i = a_im[i0];
        float u1r = a_re[i0 + q],     u1i = a_im[i0 + q];
        float u2r = a_re[i0 + 2 * q], u2i = a_im[i0 + 2 * q];
        float u3r = a_re[i0 + 3 * q], u3i = a_im[i0 + 3 * q];

        float b1r = fmaf(w1r, u1r, -w1i * u1i), b1i = fmaf(w1r, u1i, w1i * u1r);
        float b2r = fmaf(w2r, u2r, -w2i * u2i), b2i = fmaf(w2r, u2i, w2i * u2r);
        float b3r = fmaf(w3r, u3r, -w3i * u3i), b3i = fmaf(w3r, u3i, w3i * u3r);

        float t0r = b0r + b2r, t0i = b0i + b2i;
        float t1r = b0r - b2r, t1i = b0i - b2i;
        float t2r = b1r + b3r, t2i = b1i + b3i;
        float t3r = b1r - b3r, t3i = b1i - b3i;

        a_re[i0]         = t0r + t2r;  a_im[i0]         = t0i + t2i;
        a_re[i0 + q]     = t1r + t3i;  a_im[i0 + q]     = t1i - t3r;
        a_re[i0 + 2 * q] = t0r - t2r;  a_im[i0 + 2 * q] = t0i - t2i;
        a_re[i0 + 3 * q] = t1r - t3i;  a_im[i0 + 3 * q] = t1i + t3r;
        __syncthreads();
    }

    // ---- In-place real unpack + mag2.  Pair (j, 1024-j), j = 1..512:
    //   E = (Z[j]+conj(Z[jc]))/2,  O = -i(Z[j]-conj(Z[jc]))/2,  P = W_2048^j O
    //   X[j] = E + P,  X[jc] = conj(E - P).   (j=512 self-pair: exact.)
    // Each slot is read and written by exactly one thread -> no barrier
    // needed inside; one barrier after.
    if (tid == 0) { mag2[0] = -2.0f; }           // excluded bin (low_freq=1)
    #pragma unroll
    for (int r = 0; r < 2; ++r) {
        int j  = 1 + tid + 256 * r;              // 1..512
        int jc = M_SZ - j;                       // 512..1023
        float zr = a_re[j],  zi = a_im[j];
        float cr = a_re[jc], ci = a_im[jc];
        float er  = 0.5f * (zr + cr), ei = 0.5f * (zi - ci);
        float orr = 0.5f * (zi + ci), oii = -0.5f * (zr - cr);
        float ang = (float)j * (1.0f / 1024.0f);
        float twr =  cospif(ang);
        float twq = -sinpif(ang);
        float pr_ = fmaf(twr, orr, -twq * oii);
        float pi_ = fmaf(twr, oii,  twq * orr);
        float xjr = er + pr_, xji = ei + pi_;
        float xcr = er - pr_, xci = -(ei - pi_);
        a_re[j]  = xjr;  a_im[j]  = xji;
        a_re[jc] = xcr;  a_im[jc] = xci;
        mag2[j]  = xjr * xjr + xji * xji;
        mag2[jc] = xcr * xcr + xci * xci;
    }
    __syncthreads();

    // Stage 1: each wave selects top-16 of its 256-bin quarter, in registers,
    // shfl-only (no barriers). Lower index wins ties (matches lax.top_k).
    float v[4]; int jj[4];
    #pragma unroll
    for (int r = 0; r < 4; ++r) {
        jj[r] = w * 256 + r * 64 + lane;
        v[r]  = mag2[jj[r]];
    }
    float my_v = -3.0f; int my_j = 0;
    for (int it = 0; it < K_SEL; ++it) {
        float bv = -2.5f; int bj = 1 << 20;
        #pragma unroll
        for (int r = 0; r < 4; ++r)          // jj ascending: strict > keeps low j
            if (v[r] > bv) { bv = v[r]; bj = jj[r]; }
        #pragma unroll
        for (int off = 32; off; off >>= 1) {
            float ov = __shfl_xor(bv, off);
            int   oj = __shfl_xor(bj, off);
            if (ov > bv || (ov == bv && oj < bj)) { bv = ov; bj = oj; }
        }
        if (lane == it) { my_v = bv; my_j = bj; }
        #pragma unroll
        for (int r = 0; r < 4; ++r)
            if (jj[r] == bj) v[r] = -2.0f;
    }
    if (lane < K_SEL) { cand_v[w * K_SEL + lane] = my_v; cand_j[w * K_SEL + lane] = my_j; }
    __syncthreads();

    // Stage 2: wave 0 merges 64 candidates (one per lane) -> global top-16.
    if (w == 0) {
        float cv = cand_v[lane]; int cj = cand_j[lane];
        int out_j = 0;
        for (int it = 0; it < K_SEL; ++it) {
            float rv = cv; int rj = cj;
            #pragma unroll
            for (int off = 32; off; off >>= 1) {
                float ov = __shfl_xor(rv, off);
                int   oj = __shfl_xor(rj, off);
                if (ov > rv || (ov == rv && oj < rj)) { rv = ov; rj = oj; }
            }
            if (lane == it) out_j = rj;
            if (cj == rj) cv = -2.0f;
        }
        if (lane < K_SEL) {
            int j = out_j;
            sel_j [bd * K_SEL + lane] = j;
            sel_re[bd * K_SEL + lane] = a_re[j];
            sel_im[bd * K_SEL + lane] = a_im[j];
        }
    }
}

// ---------------------------------------------------------------------------
// Kernel 2: out[b,tau,d] = (1/1024) * sum_q ( Re_q*cos(2pi j_q tau/2048)
//                                           - Im_q*sin(2pi j_q tau/2048) )
// Phase recurrence: per q, evaluate cos/sin exactly at tau0 (revolution-
// domain, exact argument), then rotate by cis(2pi j/2048) for TPT steps.
// Selection triples live in registers (64B coalesced loads per lane).
// Block = 4 tau-groups x 64 d => coalesced 256B output rows.
// ---------------------------------------------------------------------------
__global__ __launch_bounds__(256) void synth_kernel(
    const int*   __restrict__ sel_j,
    const float* __restrict__ sel_re,
    const float* __restrict__ sel_im,
    float* __restrict__ out)
{
    const int bid   = blockIdx.x;          // b * NCHUNK + chunk
    const int b     = bid / NCHUNK;
    const int chunk = bid - b * NCHUNK;
    const int tid   = threadIdx.x;
    const int d     = tid & 63;
    const int tg    = tid >> 6;            // 0..3

    const int tau0 = chunk * TAUS_PER_BLOCK + tg * TPT;
    if (tau0 >= TOUT) return;              // whole thread out of range
    const int nu = (TOUT - tau0 < TPT) ? (TOUT - tau0) : TPT;

    const int g = (b * D_SZ + d) * K_SEL;  // 16-elem aligned => 64B aligned
    int   j [K_SEL];
    float re[K_SEL];
    float im[K_SEL];
    const int4*   pj = (const int4*)  (sel_j  + g);
    const float4* pr = (const float4*)(sel_re + g);
    const float4* pi = (const float4*)(sel_im + g);
    #pragma unroll
    for (int r = 0; r < 4; ++r) {
        int4   a = pj[r];
        float4 c = pr[r];
        float4 s = pi[r];
        j [4*r+0] = a.x; j [4*r+1] = a.y; j [4*r+2] = a.z; j [4*r+3] = a.w;
        re[4*r+0] = c.x; re[4*r+1] = c.y; re[4*r+2] = c.z; re[4*r+3] = c.w;
        im[4*r+0] = s.x; im[4*r+1] = s.y; im[4*r+2] = s.z; im[4*r+3] = s.w;
    }

    float acc[TPT];
    #pragma unroll
    for (int u = 0; u < TPT; ++u) acc[u] = 0.0f;

    #pragma unroll
    for (int q = 0; q < K_SEL; ++q) {
        // Exact initial phase (revolutions) and exact step rotation.
        int   ph0 = (j[q] * tau0) & (T_SZ - 1);
        float r0  = (float)ph0  * (1.0f / (float)T_SZ);   // exact /2^11
        float rw  = (float)j[q] * (1.0f / (float)T_SZ);   // exact /2^11
        float c   = __builtin_amdgcn_cosf(r0);            // cos(2*pi*r0)
        float s   = __builtin_amdgcn_sinf(r0);
        float cw  = __builtin_amdgcn_cosf(rw);
        float sw  = __builtin_amdgcn_sinf(rw);
        #pragma unroll
        for (int u = 0; u < TPT; ++u) {
            acc[u] = fmaf(re[q], c, acc[u]);
            acc[u] = fmaf(-im[q], s, acc[u]);
            float cn = fmaf(c, cw, -s * sw);
            float sn = fmaf(s, cw,  c * sw);
            c = cn; s = sn;
        }
    }

    float* ob = out + ((size_t)b * TOUT + tau0) * D_SZ + d;
    #pragma unroll
    for (int u = 0; u < TPT; ++u) {
        if (u < nu) ob[(size_t)u * D_SZ] = acc[u] * (1.0f / 1024.0f);
    }
}

// ---------------------------------------------------------------------------
extern "C" void kernel_launch(void* const* d_in, const int* in_sizes, int n_in,
                              void* d_out, int out_size, void* d_ws, size_t ws_size,
                              hipStream_t stream) {
    const float* x = (const float*)d_in[0];

    // ws layout: sel_j (64KB) | sel_re (64KB) | sel_im (64KB)
    int*   sel_j  = (int*)d_ws;
    float* sel_re = (float*)((char*)d_ws + (size_t)B_SZ * D_SZ * K_SEL * 4);
    float* sel_im = (float*)((char*)d_ws + (size_t)2 * B_SZ * D_SZ * K_SEL * 4);

    fft_topk_kernel<<<dim3(B_SZ * D_SZ), dim3(256), 0, stream>>>(
        x, sel_j, sel_re, sel_im);

    synth_kernel<<<dim3(B_SZ * NCHUNK), dim3(256), 0, stream>>>(
        sel_j, sel_re, sel_im, (float*)d_out);
}

// Round 11
// 103.736 us; speedup vs baseline: 1.1295x; 1.0336x over previous
//
#include <hip/hip_runtime.h>
#include <hip/hip_bf16.h>

// Problem constants (setup_inputs is fixed):
//   x: (B=16, T=2048, D=64) fp32, pred_len=720, k=16, low_freq=1
//   out: (16, 2768, 64) fp32
#define B_SZ 16
#define T_SZ 2048
#define D_SZ 64
#define M_SZ 1024          // complex FFT length (T/2)
#define K_SEL 16
#define TOUT 2768          // T + pred_len
#define TPT 16             // taus per thread in synth (recurrence length)
#define TAUS_PER_BLOCK (4 * TPT)                       // 64
#define NCHUNK ((TOUT + TAUS_PER_BLOCK - 1) / TAUS_PER_BLOCK)  // 44

// base-4 digit reversal of a 10-bit index (5 digits); involution.
__device__ __forceinline__ int digitrev4(int m) {
    int v = __brev((unsigned)m) >> 22;                 // 10-bit bit reversal
    return ((v & 0x155) << 1) | ((v >> 1) & 0x155);    // swap bit pairs
}

// ---------------------------------------------------------------------------
// Kernel 1: per-(b,d) real FFT of length 2048 via radix-4 complex FFT of
// 1024 (5 stages, in-place, digit-reversed loads) + in-place real unpack,
// then top-16 by |X|^2 with register-resident wave-local selection.
// (Byte-identical to the round-7 version, which passed at 107.2 us.)
// ---------------------------------------------------------------------------
__global__ __launch_bounds__(256) void fft_topk_kernel(
    const float* __restrict__ x,
    int* __restrict__ sel_j,     // (1024, 16)
    float* __restrict__ sel_re,  // (1024, 16)
    float* __restrict__ sel_im)  // (1024, 16)
{
    __shared__ __align__(16) float a_re[M_SZ], a_im[M_SZ];
    __shared__ float tw_re[768], tw_im[768];   // W_1024^k, k=0..767
    __shared__ float mag2[M_SZ];
    __shared__ float cand_v[64];
    __shared__ int   cand_j[64];

    const int bd   = blockIdx.x;         // b*64 + d
    const int b    = bd >> 6;
    const int d    = bd & 63;
    const int tid  = threadIdx.x;
    const int lane = tid & 63;
    const int w    = tid >> 6;           // wave id 0..3

    // Issue global loads FIRST (HBM latency hides under twiddle fill).
    const float* xb = x + (size_t)b * T_SZ * D_SZ + d;
    float xe[4], xo[4];
    #pragma unroll
    for (int r = 0; r < 4; ++r) {
        int pos = tid + 256 * r;
        int m   = digitrev4(pos);
        xe[r] = xb[(2 * m) * D_SZ];
        xo[r] = xb[(2 * m + 1) * D_SZ];
    }

    // Twiddles: tw[k] = e^{-2*pi*i*k/1024} (sub-ulp via cospif/sinpif).
    for (int k = tid; k < 768; k += 256) {
        float a = (float)k * (1.0f / 512.0f);
        tw_re[k] =  cospif(a);
        tw_im[k] = -sinpif(a);
    }

    #pragma unroll
    for (int r = 0; r < 4; ++r) {
        int pos = tid + 256 * r;
        a_re[pos] = xe[r];
        a_im[pos] = xo[r];
    }
    __syncthreads();

    // ---- Stage 0 (q=1): twiddle-free, contiguous float4, in-place. ----
    {
        float4* pr4 = reinterpret_cast<float4*>(a_re);
        float4* pi4 = reinterpret_cast<float4*>(a_im);
        float4 vr = pr4[tid];
        float4 vi = pi4[tid];
        float t0r = vr.x + vr.z, t0i = vi.x + vi.z;
        float t1r = vr.x - vr.z, t1i = vi.x - vi.z;
        float t2r = vr.y + vr.w, t2i = vi.y + vi.w;
        float t3r = vr.y - vr.w, t3i = vi.y - vi.w;
        vr.x = t0r + t2r;  vi.x = t0i + t2i;
        vr.y = t1r + t3i;  vi.y = t1i - t3r;
        vr.z = t0r - t2r;  vi.z = t0i - t2i;
        vr.w = t1r - t3i;  vi.w = t1i + t3r;
        pr4[tid] = vr;
        pi4[tid] = vi;
    }
    __syncthreads();

    // ---- Stages 1..4 (q=4,16,64,256): 256 radix-4 butterflies each. ----
    #pragma unroll
    for (int s = 1; s < 5; ++s) {
        const int q   = 1 << (2 * s);
        const int pos = tid & (q - 1);
        const int i0  = ((tid >> (2 * s)) << (2 * s + 2)) + pos;
        const int e   = pos << (8 - 2 * s);

        float w1r = tw_re[e],     w1i = tw_im[e];
        float w2r = tw_re[2 * e], w2i = tw_im[2 * e];
        float w3r = tw_re[3 * e], w3i = tw_im[3 * e];

        float b0r = a_re[i0],         b0i = a_im[i0];
        float u1r = a_re[i0 + q],     u1i = a_im[i0 + q];
        float u2r = a_re[i0 + 2 * q], u2i = a_im[i0 + 2 * q];
        float u3r = a_re[i0 + 3 * q], u3i = a_im[i0 + 3 * q];

        float b1r = fmaf(w1r, u1r, -w1i * u1i), b1i = fmaf(w1r, u1i, w1i * u1r);
        float b2r = fmaf(w2r, u2r, -w2i * u2i), b2i = fmaf(w2r, u2i, w2i * u2r);
        float b3r = fmaf(w3r, u3r, -w3i * u3i), b3i = fmaf(w3r, u3i, w3i * u3r);

        float t0r = b0r + b2r, t0i = b0i + b2i;
        float t1r = b0r - b2r, t1i = b0i - b2i;
        float t2r = b1r + b3r, t2i = b1i + b3i;
        float t3r = b1r - b3r, t3i = b1i - b3i;

        a_re[i0]         = t0r + t2r;  a_im[i0]         = t0i + t2i;
        a_re[i0 + q]     = t1r + t3i;  a_im[i0 + q]     = t1i - t3r;
        a_re[i0 + 2 * q] = t0r - t2r;  a_im[i0 + 2 * q] = t0i - t2i;
        a_re[i0 + 3 * q] = t1r - t3i;  a_im[i0 + 3 * q] = t1i + t3r;
        __syncthreads();
    }

    // ---- In-place real unpack + mag2.  Pair (j, 1024-j), j = 1..512. ----
    if (tid == 0) { mag2[0] = -2.0f; }           // excluded bin (low_freq=1)
    #pragma unroll
    for (int r = 0; r < 2; ++r) {
        int j  = 1 + tid + 256 * r;              // 1..512
        int jc = M_SZ - j;                       // 512..1023
        float zr = a_re[j],  zi = a_im[j];
        float cr = a_re[jc], ci = a_im[jc];
        float er  = 0.5f * (zr + cr), ei = 0.5f * (zi - ci);
        float orr = 0.5f * (zi + ci), oii = -0.5f * (zr - cr);
        float ang = (float)j * (1.0f / 1024.0f);
        float twr =  cospif(ang);
        float twq = -sinpif(ang);
        float pr_ = fmaf(twr, orr, -twq * oii);
        float pi_ = fmaf(twr, oii,  twq * orr);
        float xjr = er + pr_, xji = ei + pi_;
        float xcr = er - pr_, xci = -(ei - pi_);
        a_re[j]  = xjr;  a_im[j]  = xji;
        a_re[jc] = xcr;  a_im[jc] = xci;
        mag2[j]  = xjr * xjr + xji * xji;
        mag2[jc] = xcr * xcr + xci * xci;
    }
    __syncthreads();

    // Stage 1: each wave selects top-16 of its 256-bin quarter, in registers,
    // shfl-only (no barriers). Lower index wins ties (matches lax.top_k).
    float v[4]; int jj[4];
    #pragma unroll
    for (int r = 0; r < 4; ++r) {
        jj[r] = w * 256 + r * 64 + lane;
        v[r]  = mag2[jj[r]];
    }
    float my_v = -3.0f; int my_j = 0;
    for (int it = 0; it < K_SEL; ++it) {
        float bv = -2.5f; int bj = 1 << 20;
        #pragma unroll
        for (int r = 0; r < 4; ++r)          // jj ascending: strict > keeps low j
            if (v[r] > bv) { bv = v[r]; bj = jj[r]; }
        #pragma unroll
        for (int off = 32; off; off >>= 1) {
            float ov = __shfl_xor(bv, off);
            int   oj = __shfl_xor(bj, off);
            if (ov > bv || (ov == bv && oj < bj)) { bv = ov; bj = oj; }
        }
        if (lane == it) { my_v = bv; my_j = bj; }
        #pragma unroll
        for (int r = 0; r < 4; ++r)
            if (jj[r] == bj) v[r] = -2.0f;
    }
    if (lane < K_SEL) { cand_v[w * K_SEL + lane] = my_v; cand_j[w * K_SEL + lane] = my_j; }
    __syncthreads();

    // Stage 2: wave 0 merges 64 candidates (one per lane) -> global top-16.
    if (w == 0) {
        float cv = cand_v[lane]; int cj = cand_j[lane];
        int out_j = 0;
        for (int it = 0; it < K_SEL; ++it) {
            float rv = cv; int rj = cj;
            #pragma unroll
            for (int off = 32; off; off >>= 1) {
                float ov = __shfl_xor(rv, off);
                int   oj = __shfl_xor(rj, off);
                if (ov > rv || (ov == rv && oj < rj)) { rv = ov; rj = oj; }
            }
            if (lane == it) out_j = rj;
            if (cj == rj) cv = -2.0f;
        }
        if (lane < K_SEL) {
            int j = out_j;
            sel_j [bd * K_SEL + lane] = j;
            sel_re[bd * K_SEL + lane] = a_re[j];
            sel_im[bd * K_SEL + lane] = a_im[j];
        }
    }
}

// ---------------------------------------------------------------------------
// Kernel 2: out[b,tau,d] = (1/1024) * sum_q g_q(tau),
//   g_q(tau) = Re_q*cos(2pi j_q tau/2048) - Im_q*sin(2pi j_q tau/2048).
// Chebyshev recurrence: g(tau+1) = 2*cos(2pi j/2048)*g(tau) - g(tau-1),
// exact trig identity -> 1 FMA + 1 add per (q,tau) after exact-argument
// seeds at tau0, tau0+1 (revolution domain, 5 transcendentals per q).
// Block = 4 tau-groups x 64 d => coalesced 256B output rows.
// ---------------------------------------------------------------------------
__global__ __launch_bounds__(256) void synth_kernel(
    const int*   __restrict__ sel_j,
    const float* __restrict__ sel_re,
    const float* __restrict__ sel_im,
    float* __restrict__ out)
{
    const int bid   = blockIdx.x;          // b * NCHUNK + chunk
    const int b     = bid / NCHUNK;
    const int chunk = bid - b * NCHUNK;
    const int tid   = threadIdx.x;
    const int d     = tid & 63;
    const int tg    = tid >> 6;            // 0..3

    const int tau0 = chunk * TAUS_PER_BLOCK + tg * TPT;
    if (tau0 >= TOUT) return;              // whole thread out of range
    const int nu = (TOUT - tau0 < TPT) ? (TOUT - tau0) : TPT;

    const int g = (b * D_SZ + d) * K_SEL;  // 16-elem aligned => 64B aligned
    int   j [K_SEL];
    float re[K_SEL];
    float im[K_SEL];
    const int4*   pj = (const int4*)  (sel_j  + g);
    const float4* pr = (const float4*)(sel_re + g);
    const float4* pi = (const float4*)(sel_im + g);
    #pragma unroll
    for (int r = 0; r < 4; ++r) {
        int4   a = pj[r];
        float4 c = pr[r];
        float4 s = pi[r];
        j [4*r+0] = a.x; j [4*r+1] = a.y; j [4*r+2] = a.z; j [4*r+3] = a.w;
        re[4*r+0] = c.x; re[4*r+1] = c.y; re[4*r+2] = c.z; re[4*r+3] = c.w;
        im[4*r+0] = s.x; im[4*r+1] = s.y; im[4*r+2] = s.z; im[4*r+3] = s.w;
    }

    float acc[TPT];
    #pragma unroll
    for (int u = 0; u < TPT; ++u) acc[u] = 0.0f;

    #pragma unroll
    for (int q = 0; q < K_SEL; ++q) {
        // Exact phase arguments (revolutions) at tau0 and tau0+1.
        int   ph0 = (j[q] * tau0) & (T_SZ - 1);
        int   ph1 = (ph0 + j[q]) & (T_SZ - 1);
        float r0  = (float)ph0  * (1.0f / (float)T_SZ);   // exact /2^11
        float r1  = (float)ph1  * (1.0f / (float)T_SZ);
        float rw  = (float)j[q] * (1.0f / (float)T_SZ);
        float g0  = fmaf(re[q], __builtin_amdgcn_cosf(r0),
                         -im[q] * __builtin_amdgcn_sinf(r0));
        float g1  = fmaf(re[q], __builtin_amdgcn_cosf(r1),
                         -im[q] * __builtin_amdgcn_sinf(r1));
        float tc  = 2.0f * __builtin_amdgcn_cosf(rw);     // 2*cos(step)
        acc[0] += g0;
        acc[1] += g1;
        #pragma unroll
        for (int u = 2; u < TPT; ++u) {
            float g2 = fmaf(tc, g1, -g0);   // exact identity, fp32-stable
            acc[u] += g2;
            g0 = g1; g1 = g2;
        }
    }

    float* ob = out + ((size_t)b * TOUT + tau0) * D_SZ + d;
    #pragma unroll
    for (int u = 0; u < TPT; ++u) {
        if (u < nu) ob[(size_t)u * D_SZ] = acc[u] * (1.0f / 1024.0f);
    }
}

// ---------------------------------------------------------------------------
extern "C" void kernel_launch(void* const* d_in, const int* in_sizes, int n_in,
                              void* d_out, int out_size, void* d_ws, size_t ws_size,
                              hipStream_t stream) {
    const float* x = (const float*)d_in[0];

    // ws layout: sel_j (64KB) | sel_re (64KB) | sel_im (64KB)
    int*   sel_j  = (int*)d_ws;
    float* sel_re = (float*)((char*)d_ws + (size_t)B_SZ * D_SZ * K_SEL * 4);
    float* sel_im = (float*)((char*)d_ws + (size_t)2 * B_SZ * D_SZ * K_SEL * 4);

    fft_topk_kernel<<<dim3(B_SZ * D_SZ), dim3(256), 0, stream>>>(
        x, sel_j, sel_re, sel_im);

    synth_kernel<<<dim3(B_SZ * NCHUNK), dim3(256), 0, stream>>>(
        sel_j, sel_re, sel_im, (float*)d_out);
}